// Round 7
// baseline (1263.831 us; speedup 1.0000x reference)
//
#include <hip/hip_runtime.h>
#include <hip/hip_bf16.h>
#include <math.h>

// Problem constants (fixed by the reference)
#define N_NODES 20000
#define T_STEPS 8
#define DDIM    256      // D_IN == D_HID == K
#define DOUT    64
#define NE      320000
#define XSTR    2048     // T_STEPS * DDIM

typedef unsigned short u16;
typedef __attribute__((ext_vector_type(8))) short  short8;   // 8 bf16 = 4 VGPR
typedef __attribute__((ext_vector_type(8))) unsigned short ushort8;
typedef __attribute__((ext_vector_type(4))) float  f32x4;

__device__ __forceinline__ float bf2f(u16 u) {
    union { unsigned int i; float f; } v; v.i = ((unsigned int)u) << 16; return v.f;
}
__device__ __forceinline__ u16 f2bf(float f) {   // RNE
    union { float f; unsigned int i; } v; v.f = f;
    unsigned int r = v.i + 0x7fff + ((v.i >> 16) & 1);
    return (u16)(r >> 16);
}

// ---------------------------------------------------------------------------
// CSR build
// ---------------------------------------------------------------------------
__global__ void k_count(const int* __restrict__ dst, int* __restrict__ cnt) {
    int e = blockIdx.x * blockDim.x + threadIdx.x;
    if (e < NE) atomicAdd(&cnt[dst[e]], 1);
}

__global__ void k_degnorm(const int* __restrict__ cnt, float* __restrict__ dis,
                          float* __restrict__ snorm) {
    int n = blockIdx.x * blockDim.x + threadIdx.x;
    if (n < N_NODES) {
        float deg = (float)(cnt[n] + 1);   // +1 self loop
        dis[n]   = rsqrtf(deg);
        snorm[n] = 1.0f / deg;
    }
}

__global__ void k_scan(const int* __restrict__ cnt, int* __restrict__ rowptr) {
    __shared__ int sums[256];
    const int CH = (N_NODES + 255) / 256;   // 79
    int t = threadIdx.x;
    int beg = t * CH;
    int end = beg + CH; if (end > N_NODES) end = N_NODES;
    int s = 0;
    for (int i = beg; i < end; i++) s += cnt[i];
    sums[t] = s;
    __syncthreads();
    if (t == 0) {
        int run = 0;
        for (int i = 0; i < 256; i++) { int v = sums[i]; sums[i] = run; run += v; }
    }
    __syncthreads();
    if (beg < N_NODES) {
        int run = sums[t];
        for (int i = beg; i < end; i++) { rowptr[i] = run; run += cnt[i]; }
        if (end == N_NODES) rowptr[N_NODES] = run;
    }
}

__global__ void k_fill(const int* __restrict__ src, const int* __restrict__ dst,
                       const int* __restrict__ rowptr, int* __restrict__ cursor,
                       const float* __restrict__ dis, int* __restrict__ csr_src,
                       float* __restrict__ csr_norm) {
    int e = blockIdx.x * blockDim.x + threadIdx.x;
    if (e < NE) {
        int d = dst[e], s = src[e];
        int pos = atomicAdd(&cursor[d], 1);
        int i = rowptr[d] + pos;
        if (i < NE) {
            csr_src[i]  = s;
            csr_norm[i] = dis[s] * dis[d];
        }
    }
}

// ---------------------------------------------------------------------------
// Weight pack: BTpack[by][tile][c][k], by=0..3 (64-col groups), tile=0..5:
// {0:W_xr, 1:W_xz, 2:W_hn, 3:W_hr, 4:W_hz, 5:W_hn}, value = W[k][by*64+c] bf16
// ---------------------------------------------------------------------------
__global__ void k_pack6(const float* __restrict__ Wxr, const float* __restrict__ Wxz,
                        const float* __restrict__ Whn, const float* __restrict__ Whr,
                        const float* __restrict__ Whz, u16* __restrict__ out) {
    int i = blockIdx.x * blockDim.x + threadIdx.x;   // over 4*6*64*256
    if (i >= 4 * 6 * 64 * 256) return;
    int k    = i & 255;
    int c    = (i >> 8) & 63;
    int tile = (i >> 14) % 6;
    int by   = i / (6 * 64 * 256);
    const float* W;
    switch (tile) {
        case 0: W = Wxr; break; case 1: W = Wxz; break; case 2: W = Whn; break;
        case 3: W = Whr; break; case 4: W = Whz; break; default: W = Whn; break;
    }
    out[i] = f2bf(W[k * DDIM + by * 64 + c]);
}
// bias3 = [b_xr+b_hr | b_xz+b_hz | b_hn]
__global__ void k_packb3(const float* __restrict__ bxr, const float* __restrict__ bhr,
                         const float* __restrict__ bxz, const float* __restrict__ bhz,
                         const float* __restrict__ bhn, float* __restrict__ bout) {
    int c = blockIdx.x * blockDim.x + threadIdx.x;
    if (c < 3 * DDIM) {
        float v;
        if (c < 256)      v = bxr[c] + bhr[c];
        else if (c < 512) v = bxz[c - 256] + bhz[c - 256];
        else              v = bhn[c - 512];
        bout[c] = v;
    }
}

// ---------------------------------------------------------------------------
// all-timestep x -> bf16 [N][2048]
// ---------------------------------------------------------------------------
__global__ __launch_bounds__(256) void k_x2bf_all(const float* __restrict__ x,
                                                  u16* __restrict__ out) {
    int i = blockIdx.x * blockDim.x + threadIdx.x;   // over N*512 ushort4 chunks
    if (i >= N_NODES * 512) return;
    size_t o = (size_t)i << 2;
    float4 v = *(const float4*)(x + o);
    ushort4 u; u.x = f2bf(v.x); u.y = f2bf(v.y); u.z = f2bf(v.z); u.w = f2bf(v.w);
    *(ushort4*)(out + o) = u;
}

// ---------------------------------------------------------------------------
// Batched x aggregation over all 8 timesteps.
// Lane mapping: th = lane>>5 picks timesteps th*4..th*4+3; c8 = (lane&31)*8.
// Per edge per lane: 4 x ushort8 (16B) loads. Unroll x4 with NAMED scalars
// so the 16 loads stay independent and in flight (MLP).
// ---------------------------------------------------------------------------
#define XLOAD(G, sp) \
    ushort8 G##0 = *(const ushort8*)((sp));        \
    ushort8 G##1 = *(const ushort8*)((sp) + 256);  \
    ushort8 G##2 = *(const ushort8*)((sp) + 512);  \
    ushort8 G##3 = *(const ushort8*)((sp) + 768);
#define XACC(G, W) {                                        \
    _Pragma("unroll")                                       \
    for (int q = 0; q < 8; q++) {                           \
        acc0[q] = fmaf(bf2f(G##0[q]), (W), acc0[q]);        \
        acc1[q] = fmaf(bf2f(G##1[q]), (W), acc1[q]);        \
        acc2[q] = fmaf(bf2f(G##2[q]), (W), acc2[q]);        \
        acc3[q] = fmaf(bf2f(G##3[q]), (W), acc3[q]);        \
    } }

__global__ __launch_bounds__(256) void k_agg_x(const u16* __restrict__ xall,
                      const int* __restrict__ rowptr, const int* __restrict__ csr_src,
                      const float* __restrict__ csr_norm, const float* __restrict__ snorm,
                      u16* __restrict__ xaall) {
    int lane = threadIdx.x & 63;
    int th   = lane >> 5;            // timestep half
    int c8   = (lane & 31) << 3;     // column chunk (8 cols)
    int off  = th * 1024 + c8;       // element offset of t = th*4, col c8
    int wid  = blockIdx.x * 4 + (threadIdx.x >> 6);
    int nw   = gridDim.x * 4;
    for (int n = wid; n < N_NODES; n += nw) {
        float sn = snorm[n];
        const u16* selfp = xall + (size_t)n * XSTR + off;
        float acc0[8], acc1[8], acc2[8], acc3[8];
        {
            XLOAD(s, selfp)
#pragma unroll
            for (int q = 0; q < 8; q++) {
                acc0[q] = bf2f(s0[q]) * sn; acc1[q] = bf2f(s1[q]) * sn;
                acc2[q] = bf2f(s2[q]) * sn; acc3[q] = bf2f(s3[q]) * sn;
            }
        }
        int beg = rowptr[n], end = rowptr[n + 1];
        int i = beg;
        for (; i + 3 < end; i += 4) {
            const u16* spA = xall + (size_t)csr_src[i]     * XSTR + off;
            const u16* spB = xall + (size_t)csr_src[i + 1] * XSTR + off;
            const u16* spC = xall + (size_t)csr_src[i + 2] * XSTR + off;
            const u16* spD = xall + (size_t)csr_src[i + 3] * XSTR + off;
            float wA = csr_norm[i], wB = csr_norm[i + 1];
            float wC = csr_norm[i + 2], wD = csr_norm[i + 3];
            XLOAD(a, spA) XLOAD(b, spB) XLOAD(c, spC) XLOAD(d, spD)
            XACC(a, wA) XACC(b, wB) XACC(c, wC) XACC(d, wD)
        }
        for (; i < end; i++) {
            const u16* sp = xall + (size_t)csr_src[i] * XSTR + off;
            float w = csr_norm[i];
            XLOAD(a, sp)
            XACC(a, w)
        }
        u16* op = xaall + (size_t)n * XSTR + off;
        ushort8 o0, o1, o2, o3;
#pragma unroll
        for (int q = 0; q < 8; q++) {
            o0[q] = f2bf(acc0[q]); o1[q] = f2bf(acc1[q]);
            o2[q] = f2bf(acc2[q]); o3[q] = f2bf(acc3[q]);
        }
        *(ushort8*)(op)       = o0;
        *(ushort8*)(op + 256) = o1;
        *(ushort8*)(op + 512) = o2;
        *(ushort8*)(op + 768) = o3;
    }
}

// ---------------------------------------------------------------------------
// Per-step h aggregation (bf16 in/out), named-scalar unroll x4, grid-stride
// ---------------------------------------------------------------------------
__global__ __launch_bounds__(256) void k_agg_bf(const u16* __restrict__ in,
                      const int* __restrict__ rowptr, const int* __restrict__ csr_src,
                      const float* __restrict__ csr_norm, const float* __restrict__ snorm,
                      u16* __restrict__ out) {
    int lane = threadIdx.x & 63;
    int c4 = lane << 2;
    int wid = blockIdx.x * 4 + (threadIdx.x >> 6);
    int nw  = gridDim.x * 4;
    for (int n = wid; n < N_NODES; n += nw) {
        float sn = snorm[n];
        ushort4 v = *(const ushort4*)(in + (size_t)n * DDIM + c4);
        float a0 = bf2f(v.x) * sn, a1 = bf2f(v.y) * sn;
        float a2 = bf2f(v.z) * sn, a3 = bf2f(v.w) * sn;
        int beg = rowptr[n], end = rowptr[n + 1];
        int i = beg;
        for (; i + 3 < end; i += 4) {
            ushort4 gA = *(const ushort4*)(in + (size_t)csr_src[i]     * DDIM + c4);
            ushort4 gB = *(const ushort4*)(in + (size_t)csr_src[i + 1] * DDIM + c4);
            ushort4 gC = *(const ushort4*)(in + (size_t)csr_src[i + 2] * DDIM + c4);
            ushort4 gD = *(const ushort4*)(in + (size_t)csr_src[i + 3] * DDIM + c4);
            float wA = csr_norm[i], wB = csr_norm[i + 1];
            float wC = csr_norm[i + 2], wD = csr_norm[i + 3];
            a0 = fmaf(bf2f(gA.x), wA, a0); a1 = fmaf(bf2f(gA.y), wA, a1);
            a2 = fmaf(bf2f(gA.z), wA, a2); a3 = fmaf(bf2f(gA.w), wA, a3);
            a0 = fmaf(bf2f(gB.x), wB, a0); a1 = fmaf(bf2f(gB.y), wB, a1);
            a2 = fmaf(bf2f(gB.z), wB, a2); a3 = fmaf(bf2f(gB.w), wB, a3);
            a0 = fmaf(bf2f(gC.x), wC, a0); a1 = fmaf(bf2f(gC.y), wC, a1);
            a2 = fmaf(bf2f(gC.z), wC, a2); a3 = fmaf(bf2f(gC.w), wC, a3);
            a0 = fmaf(bf2f(gD.x), wD, a0); a1 = fmaf(bf2f(gD.y), wD, a1);
            a2 = fmaf(bf2f(gD.z), wD, a2); a3 = fmaf(bf2f(gD.w), wD, a3);
        }
        for (; i < end; i++) {
            ushort4 g = *(const ushort4*)(in + (size_t)csr_src[i] * DDIM + c4);
            float w = csr_norm[i];
            a0 = fmaf(bf2f(g.x), w, a0); a1 = fmaf(bf2f(g.y), w, a1);
            a2 = fmaf(bf2f(g.z), w, a2); a3 = fmaf(bf2f(g.w), w, a3);
        }
        ushort4 o; o.x = f2bf(a0); o.y = f2bf(a1); o.z = f2bf(a2); o.w = f2bf(a3);
        *(ushort4*)(out + (size_t)n * DDIM + c4) = o;
    }
}

// ---------------------------------------------------------------------------
// Fused gate GEMM + GRU update. Block: 128 rows x 64 h-cols (blockIdx.y=by).
// 4 waves (2 row x 2 col): per wave 64 rows x 32 cols.
//   r  = xa@W_xr + ha@W_hr    z = xa@W_xz + ha@W_hz
//   nx = xa@W_hn              nh = ha@W_hn
// h_new = (1-sig(z+bz))*h + sig(z+bz)*tanh(nx+bn + sig(r+br)*(nh+bn))
// LDS chunk-XOR swizzle on all tiles (involution on stage + read, verified r6).
// ---------------------------------------------------------------------------
__device__ __forceinline__ float sigm(float x) { return 1.0f / (1.0f + expf(-x)); }

__global__ __launch_bounds__(256) void k_gate_gru(const u16* __restrict__ xa, int ldax,
        const u16* __restrict__ ha, const u16* __restrict__ BTpack,
        const float* __restrict__ bias3, float* __restrict__ h, u16* __restrict__ hbf,
        int M) {
    __shared__ u16 Axs[128 * 32];    // 8KB
    __shared__ u16 Ahs[128 * 32];    // 8KB
    __shared__ u16 Bs[6 * 64 * 32];  // 24KB
    int tid = threadIdx.x;
    int w = tid >> 6, lane = tid & 63;
    int wr = w >> 1, wcol = w & 1;
    int rowBase = blockIdx.x * 128;
    int by = blockIdx.y;             // 0..3

    // staging: lane covers row srow (within 16-row segment), swizzled chunk
    int srow  = lane >> 2;                       // 0..15
    int chunk = (lane & 3) ^ ((lane >> 3) & 3);  // involution partner
    int sege  = chunk * 8;                       // elements
    int arow0 = rowBase + w * 16 + srow;         // A rows seg 0 (block rows 0..63)
    int arow1 = arow0 + 64;                      // A rows seg 1 (64..127)
    if (arow0 > M - 1) arow0 = M - 1;
    if (arow1 > M - 1) arow1 = M - 1;
    size_t xoff0 = (size_t)arow0 * ldax + sege;
    size_t xoff1 = (size_t)arow1 * ldax + sege;
    size_t hoff0 = (size_t)arow0 * DDIM + sege;
    size_t hoff1 = (size_t)arow1 * DDIM + sege;
    u16* ldsAx0 = &Axs[w * 512];
    u16* ldsAx1 = &Axs[2048 + w * 512];
    u16* ldsAh0 = &Ahs[w * 512];
    u16* ldsAh1 = &Ahs[2048 + w * 512];
    const u16* Bbase = BTpack + (size_t)by * (6 * 64 * 256);

    f32x4 ar[4][2], az[4][2], anx[4][2], anh[4][2];
#pragma unroll
    for (int m = 0; m < 4; m++)
#pragma unroll
        for (int n = 0; n < 2; n++) {
            ar[m][n] = (f32x4){0.f,0.f,0.f,0.f}; az[m][n] = (f32x4){0.f,0.f,0.f,0.f};
            anx[m][n] = (f32x4){0.f,0.f,0.f,0.f}; anh[m][n] = (f32x4){0.f,0.f,0.f,0.f};
        }

    int kq = lane >> 4, lr = lane & 15;
    int kqs = (kq ^ ((lr >> 1) & 3)) << 3;       // swizzled read chunk (elems)

    for (int k0 = 0; k0 < DDIM; k0 += 32) {
        __builtin_amdgcn_global_load_lds(
            (const __attribute__((address_space(1))) void*)(xa + xoff0 + k0),
            (__attribute__((address_space(3))) void*)ldsAx0, 16, 0, 0);
        __builtin_amdgcn_global_load_lds(
            (const __attribute__((address_space(1))) void*)(xa + xoff1 + k0),
            (__attribute__((address_space(3))) void*)ldsAx1, 16, 0, 0);
        __builtin_amdgcn_global_load_lds(
            (const __attribute__((address_space(1))) void*)(ha + hoff0 + k0),
            (__attribute__((address_space(3))) void*)ldsAh0, 16, 0, 0);
        __builtin_amdgcn_global_load_lds(
            (const __attribute__((address_space(1))) void*)(ha + hoff1 + k0),
            (__attribute__((address_space(3))) void*)ldsAh1, 16, 0, 0);
#pragma unroll
        for (int j = 0; j < 6; j++) {   // B tile j: 64 rows, wave covers 16
            const u16* srcp = Bbase + ((size_t)j * 64 + w * 16 + srow) * 256 + k0 + sege;
            u16* dstp = &Bs[j * 2048 + w * 512];
            __builtin_amdgcn_global_load_lds(
                (const __attribute__((address_space(1))) void*)srcp,
                (__attribute__((address_space(3))) void*)dstp, 16, 0, 0);
        }
        __syncthreads();

        short8 axf[4], ahf[4], bf[6][2];
#pragma unroll
        for (int m = 0; m < 4; m++) {
            int r = wr * 64 + m * 16 + lr;
            axf[m] = *(const short8*)&Axs[r * 32 + kqs];
            ahf[m] = *(const short8*)&Ahs[r * 32 + kqs];
        }
#pragma unroll
        for (int t = 0; t < 6; t++)
#pragma unroll
            for (int n = 0; n < 2; n++) {
                int c = wcol * 32 + n * 16 + lr;
                bf[t][n] = *(const short8*)&Bs[t * 2048 + c * 32 + kqs];
            }
#pragma unroll
        for (int m = 0; m < 4; m++)
#pragma unroll
            for (int n = 0; n < 2; n++) {
                ar[m][n]  = __builtin_amdgcn_mfma_f32_16x16x32_bf16(axf[m], bf[0][n], ar[m][n], 0, 0, 0);
                ar[m][n]  = __builtin_amdgcn_mfma_f32_16x16x32_bf16(ahf[m], bf[3][n], ar[m][n], 0, 0, 0);
                az[m][n]  = __builtin_amdgcn_mfma_f32_16x16x32_bf16(axf[m], bf[1][n], az[m][n], 0, 0, 0);
                az[m][n]  = __builtin_amdgcn_mfma_f32_16x16x32_bf16(ahf[m], bf[4][n], az[m][n], 0, 0, 0);
                anx[m][n] = __builtin_amdgcn_mfma_f32_16x16x32_bf16(axf[m], bf[2][n], anx[m][n], 0, 0, 0);
                anh[m][n] = __builtin_amdgcn_mfma_f32_16x16x32_bf16(ahf[m], bf[5][n], anh[m][n], 0, 0, 0);
            }
        __syncthreads();
    }

    // fused GRU epilogue
#pragma unroll
    for (int n = 0; n < 2; n++) {
        int col = by * 64 + wcol * 32 + n * 16 + lr;
        float br = bias3[col], bz = bias3[256 + col], bn = bias3[512 + col];
#pragma unroll
        for (int m = 0; m < 4; m++) {
            int row0 = rowBase + wr * 64 + m * 16 + kq * 4;
#pragma unroll
            for (int j = 0; j < 4; j++) {
                int row = row0 + j;
                if (row < M) {
                    float r = sigm(ar[m][n][j] + br);
                    float z = sigm(az[m][n][j] + bz);
                    float nn = tanhf(anx[m][n][j] + bn + r * (anh[m][n][j] + bn));
                    size_t idx = (size_t)row * DDIM + col;
                    float hv = h[idx];
                    hv = (1.0f - z) * hv + z * nn;
                    h[idx] = hv;
                    hbf[idx] = f2bf(hv);
                }
            }
        }
    }
}

// ---------------------------------------------------------------------------
// fp32 SIMT GEMM (final FC only)
// ---------------------------------------------------------------------------
__global__ __launch_bounds__(256) void k_gemm(const float* __restrict__ A,
        const float* __restrict__ B, const float* __restrict__ bias,
        float* __restrict__ C, int M, int N, int K) {
    __shared__ float Asm[16][132];
    __shared__ float Bsm[16][128];
    int tid = threadIdx.x;
    int tx = tid & 15, ty = tid >> 4;
    int rowBase = blockIdx.x * 128;
    int colBase = blockIdx.y * 128;

    float acc[8][8];
#pragma unroll
    for (int i = 0; i < 8; i++)
#pragma unroll
        for (int j = 0; j < 8; j++) acc[i][j] = 0.0f;

    int arow = tid >> 1;
    int acol = (tid & 1) * 8;
    int brow = tid >> 4;
    int bcol = (tid & 15) * 8;

    bool avalid = (rowBase + arow) < M;
    const float* Aptr = A + (size_t)(rowBase + arow) * K + acol;
    int bc = colBase + bcol;
    bool bvalid = bc < N;

    for (int k0 = 0; k0 < K; k0 += 16) {
        float4 a0 = {0,0,0,0}, a1 = {0,0,0,0};
        if (avalid) {
            a0 = *(const float4*)(Aptr + k0);
            a1 = *(const float4*)(Aptr + k0 + 4);
        }
        Asm[acol + 0][arow] = a0.x; Asm[acol + 1][arow] = a0.y;
        Asm[acol + 2][arow] = a0.z; Asm[acol + 3][arow] = a0.w;
        Asm[acol + 4][arow] = a1.x; Asm[acol + 5][arow] = a1.y;
        Asm[acol + 6][arow] = a1.z; Asm[acol + 7][arow] = a1.w;

        float4 b0 = {0,0,0,0}, b1 = {0,0,0,0};
        if (bvalid) {
            const float* Bp = B + (size_t)(k0 + brow) * N + bc;
            b0 = *(const float4*)(Bp);
            b1 = *(const float4*)(Bp + 4);
        }
        *(float4*)&Bsm[brow][bcol]     = b0;
        *(float4*)&Bsm[brow][bcol + 4] = b1;
        __syncthreads();

#pragma unroll
        for (int k = 0; k < 16; k++) {
            float a[8], b[8];
            *(float4*)&a[0] = *(const float4*)&Asm[k][ty * 8];
            *(float4*)&a[4] = *(const float4*)&Asm[k][ty * 8 + 4];
            *(float4*)&b[0] = *(const float4*)&Bsm[k][tx * 8];
            *(float4*)&b[4] = *(const float4*)&Bsm[k][tx * 8 + 4];
#pragma unroll
            for (int i = 0; i < 8; i++)
#pragma unroll
                for (int j = 0; j < 8; j++)
                    acc[i][j] = fmaf(a[i], b[j], acc[i][j]);
        }
        __syncthreads();
    }

    int c0 = colBase + tx * 8;
    if (c0 < N) {
        float4 bia0 = *(const float4*)(bias + c0);
        float4 bia1 = *(const float4*)(bias + c0 + 4);
#pragma unroll
        for (int i = 0; i < 8; i++) {
            int r = rowBase + ty * 8 + i;
            if (r < M) {
                float4 o0, o1;
                o0.x = acc[i][0] + bia0.x; o0.y = acc[i][1] + bia0.y;
                o0.z = acc[i][2] + bia0.z; o0.w = acc[i][3] + bia0.w;
                o1.x = acc[i][4] + bia1.x; o1.y = acc[i][5] + bia1.y;
                o1.z = acc[i][6] + bia1.z; o1.w = acc[i][7] + bia1.w;
                *(float4*)(C + (size_t)r * N + c0)     = o0;
                *(float4*)(C + (size_t)r * N + c0 + 4) = o1;
            }
        }
    }
}

// ---------------------------------------------------------------------------
extern "C" void kernel_launch(void* const* d_in, const int* in_sizes, int n_in,
                              void* d_out, int out_size, void* d_ws, size_t ws_size,
                              hipStream_t stream) {
    const float* x    = (const float*)d_in[0];
    const int*   eidx = (const int*)d_in[1];
    const int*   src  = eidx;
    const int*   dst  = eidx + NE;
    const float* W_xr = (const float*)d_in[2];  const float* b_xr = (const float*)d_in[3];
    const float* W_hr = (const float*)d_in[4];  const float* b_hr = (const float*)d_in[5];
    const float* W_xz = (const float*)d_in[6];  const float* b_xz = (const float*)d_in[7];
    const float* W_hz = (const float*)d_in[8];  const float* b_hz = (const float*)d_in[9];
    const float* W_hn = (const float*)d_in[10]; const float* b_hn = (const float*)d_in[11];
    const float* W_fc = (const float*)d_in[12]; const float* b_fc = (const float*)d_in[13];
    float* out = (float*)d_out;

    char* ws = (char*)d_ws;
    size_t off = 0;
    auto alloc = [&](size_t bytes) -> char* {
        char* p = ws + off;
        off += (bytes + 255) & ~(size_t)255;
        return p;
    };
    const size_t NB  = (size_t)N_NODES * DDIM * 4;    // 20.5 MB fp32
    const size_t NBH = (size_t)N_NODES * DDIM * 2;    // 10.2 MB bf16
    u16*   xall    = (u16*)alloc((size_t)N_NODES * XSTR * 2);   // 81.9 MB
    u16*   xaall   = (u16*)alloc((size_t)N_NODES * XSTR * 2);   // 81.9 MB
    float* h       = (float*)alloc(NB);
    u16*   hbf     = (u16*)alloc(NBH);
    u16*   ha      = (u16*)alloc(NBH);
    u16*   BTpack  = (u16*)alloc((size_t)4 * 6 * 64 * 256 * 2); // 0.79 MB
    float* bias3   = (float*)alloc(3 * DDIM * 4);
    int*   cnt     = (int*)alloc(N_NODES * 4);
    int*   cursor  = (int*)alloc(N_NODES * 4);
    int*   rowptr  = (int*)alloc((N_NODES + 1) * 4);
    int*   csr_src = (int*)alloc(NE * 4);
    float* csr_nrm = (float*)alloc(NE * 4);
    float* dis     = (float*)alloc(N_NODES * 4);
    float* snorm   = (float*)alloc(N_NODES * 4);

    hipMemsetAsync(cnt, 0, N_NODES * 4, stream);
    hipMemsetAsync(cursor, 0, N_NODES * 4, stream);
    hipMemsetAsync(h, 0, NB, stream);
    hipMemsetAsync(hbf, 0, NBH, stream);

    const int TB = 256;
    // CSR build + norms
    k_count<<<(NE + TB - 1) / TB, TB, 0, stream>>>(dst, cnt);
    k_degnorm<<<(N_NODES + TB - 1) / TB, TB, 0, stream>>>(cnt, dis, snorm);
    k_scan<<<1, 256, 0, stream>>>(cnt, rowptr);
    k_fill<<<(NE + TB - 1) / TB, TB, 0, stream>>>(src, dst, rowptr, cursor, dis,
                                                  csr_src, csr_nrm);
    // weight/bias packing
    k_pack6<<<(4 * 6 * 64 * 256 + TB - 1) / TB, TB, 0, stream>>>(W_xr, W_xz, W_hn,
                                                                 W_hr, W_hz, BTpack);
    k_packb3<<<(3 * DDIM + TB - 1) / TB, TB, 0, stream>>>(b_xr, b_hr, b_xz, b_hz,
                                                          b_hn, bias3);

    // batched x-side prep
    k_x2bf_all<<<(N_NODES * 512 + TB - 1) / TB, TB, 0, stream>>>(x, xall);
    k_agg_x<<<2048, TB, 0, stream>>>(xall, rowptr, csr_src, csr_nrm, snorm, xaall);

    dim3 gGate((N_NODES + 127) / 128, 4);   // 157 x 4
    dim3 gfc((N_NODES + 127) / 128, 1);

    for (int t = 0; t < T_STEPS; t++) {
        k_agg_bf<<<2048, TB, 0, stream>>>(hbf, rowptr, csr_src, csr_nrm, snorm, ha);
        k_gate_gru<<<gGate, TB, 0, stream>>>(xaall + t * DDIM, XSTR, ha, BTpack,
                                             bias3, h, hbf, N_NODES);
    }
    // final FC in fp32: out = h @ W_fc + b_fc
    k_gemm<<<gfc, TB, 0, stream>>>(h, W_fc, b_fc, out, N_NODES, DOUT, DDIM);
}